// Round 9
// baseline (43.271 us; speedup 1.0000x reference)
//
#include <hip/hip_runtime.h>
#include <math.h>

#define W_ 128
#define H_ 96
#define C_ 128
#define HW_ (H_ * W_)          // 12288
#define NPX (2 * HW_)          // 24576 pixels total
#define K_ 81
#define FLOW_ELEMS (2 * 2 * H_ * W_)   // 49152

// ---------------- corr kernel ----------------
// One 64-thread block (= one wave) per (b, y0, dg, chalf):
//   dg in 0..8 -> dy = dg-4 ; chalf selects channels [chalf*64, chalf*64+64).
// The wave accumulates its 64 channels for halo row r = y0+dg-4 and writes the
// k-slice [dg*9, dg*9+9) PARTIAL sums into transposed scratch planes:
//   scratch[half*81 + k][b*HW + y0*W + px]   (coalesced, stride-2 per lane)
// 3456 blocks = 8 XCD chunks x 432. Lane owns pixels x = 2*lane, 2*lane+1.
__global__ __launch_bounds__(64) void corr_kernel(const float* __restrict__ f0,
                                                  const float* __restrict__ f1,
                                                  float* __restrict__ scratch) {
    __shared__ float lds[8][136];   // 8-channel chunk of the halo row (4352 B)

    const int lane = threadIdx.x;

    // XCD-bijective swizzle: 3456 = 8 * 432
    const int L = (blockIdx.x & 7) * 432 + (blockIdx.x >> 3);
    const int half = L & 1;
    const int L2 = L >> 1;               // 0..1727
    const int dg = L2 % 9;
    const int rid = L2 / 9;              // 0..191
    const int y0 = rid % H_;
    const int b  = rid / H_;
    const int r  = y0 + dg - 4;          // halo row in f1 (may be OOB)
    const bool rok = (r >= 0) && (r < H_);

    // staging: lane q stages quad q covering f1 columns q*4-4 .. q*4-1;
    // LDS word w holds column w-4. Quads 0 and 33 are fully OOB -> zeros.
    const int q = lane;
    const bool qok = rok && (q >= 1) && (q <= 32);
    const int cbase = half * 64;
    const float* f0p = f0 + (size_t)b * C_ * HW_ + (size_t)cbase * HW_
                          + (size_t)y0 * W_ + 2 * lane;
    const float* f1p = f1 + (size_t)b * C_ * HW_ + (size_t)cbase * HW_
                          + (size_t)(rok ? r : 0) * W_ + (q * 4 - 4);

    float acc0[9], acc1[9];
#pragma unroll
    for (int j = 0; j < 9; ++j) { acc0[j] = 0.f; acc1[j] = 0.f; }

    // ---- load chunk ck (8 channels of this wave's 64) into named regs ----
    auto LOAD = [&](int ck, float4 (&v)[8], float2 (&g)[8]) {
#pragma unroll
        for (int cc = 0; cc < 8; ++cc) {
            const size_t co = (size_t)(ck * 8 + cc) * HW_;
            g[cc] = *(const float2*)(f0p + co);
            float4 t = make_float4(0.f, 0.f, 0.f, 0.f);
            if (qok) t = *(const float4*)(f1p + co);
            v[cc] = t;
        }
    };

    // ---- stage to LDS (compiler-fenced; 1-wave block, DS-pipe order) ----
    auto CONSUME = [&](const float4 (&v)[8], const float2 (&g)[8]) {
        __builtin_amdgcn_sched_barrier(0);
        if (q < 34) {
#pragma unroll
            for (int cc = 0; cc < 8; ++cc)
                *(float4*)&lds[cc][q * 4] = v[cc];
        }
        __builtin_amdgcn_sched_barrier(0);
#pragma unroll
        for (int cc = 0; cc < 8; ++cc) {
            const float2* row = (const float2*)(&lds[cc][0]) + lane;
            const float2 w0 = row[0], w1 = row[1], w2 = row[2],
                         w3 = row[3], w4 = row[4];
            const float vv[10] = {w0.x, w0.y, w1.x, w1.y, w2.x,
                                  w2.y, w3.x, w3.y, w4.x, w4.y};
#pragma unroll
            for (int dx = 0; dx < 9; ++dx) {
                acc0[dx] += g[cc].x * vv[dx];
                acc1[dx] += g[cc].y * vv[dx + 1];
            }
        }
    };

    float4 vA[8], vB[8];
    float2 gA[8], gB[8];

    // 8 chunks: A consumes 0,2,4,6; B consumes 1,3,5,7.
    LOAD(0, vA, gA);
    for (int it = 0; it < 4; ++it) {
        LOAD(2 * it + 1, vB, gB);
        CONSUME(vA, gA);
        if (it < 3) LOAD(2 * it + 2, vA, gA);
        CONSUME(vB, gB);
    }

    // ---- coalesced transposed writeout: plane = half*81 + dg*9 + j ----
    float* sp = scratch + (size_t)(half * K_ + dg * 9) * NPX
                        + (size_t)b * HW_ + (size_t)y0 * W_;
#pragma unroll
    for (int j = 0; j < 9; ++j) {
        sp[2 * lane] = acc0[j];
        sp[2 * lane + 1] = acc1[j];
        sp += NPX;
    }
}

// ---------------- softmax kernel ----------------
// Block = 256 thr (4 waves) handles a 64-px tile. Gathers the 162 partial
// planes (coalesced 256B rows), sums halves into LDS tile[81][69], then
// thread-per-px softmax (2 scans) + flow, then all threads write match_prob.
__global__ __launch_bounds__(256) void softmax_kernel(const float* __restrict__ scratch,
                                                      float* __restrict__ out) {
    __shared__ float tile[K_][69];    // 22356 B, odd stride -> <=2-way conflicts
    __shared__ float mbuf[64], ibuf[64];

    const int t = threadIdx.x;
    const int wid = t >> 6, lane = t & 63;
    const int bid = blockIdx.x;              // 0..383
    const int b = bid / 192;
    const int rem = bid - b * 192;
    const int y0 = rem >> 1;
    const int x0 = (rem & 1) << 6;
    const size_t pxbase = (size_t)b * HW_ + (size_t)y0 * W_ + x0;

    // ---- gather: wave w handles k = w, w+4, ... ; reads both halves ----
    for (int k = wid; k < K_; k += 4) {
        const float v0 = scratch[(size_t)k * NPX + pxbase + lane];
        const float v1 = scratch[(size_t)(K_ + k) * NPX + pxbase + lane];
        tile[k][lane] = v0 + v1;
    }
    __syncthreads();

    // ---- pass 1: thread-per-px (t < 64) max / sum-exp / flow ----
    if (t < 64) {
        const float scale = 0.08838834764831845f;   // 1/sqrt(128)
        float m = -1e30f;
#pragma unroll 9
        for (int k = 0; k < K_; ++k) m = fmaxf(m, tile[k][t] * scale);
        float s = 0.f, fx = 0.f, fy = 0.f;
#pragma unroll 9
        for (int k = 0; k < K_; ++k) {
            const float e = __expf(tile[k][t] * scale - m);
            s += e;
            fx += e * (float)(k % 9 - 4);
            fy += e * (float)(k / 9 - 4);
        }
        const float inv = 1.f / s;
        mbuf[t] = m;
        ibuf[t] = inv;
        const size_t fbase = (size_t)b * 2 * HW_ + (size_t)y0 * W_ + x0 + t;
        out[fbase] = fx * inv;
        out[fbase + HW_] = fy * inv;
    }
    __syncthreads();

    // ---- pass 2: all 256 threads write match_prob coalesced ----
    const float scale = 0.08838834764831845f;
    float* mp = out + FLOW_ELEMS + pxbase * K_;   // match_prob is [b][hw][81]
    for (int i = t; i < 64 * K_; i += 256) {
        const int px = i / K_;
        const int k = i - px * K_;
        mp[(size_t)px * K_ + k] =
            __expf(tile[k][px] * scale - mbuf[px]) * ibuf[px];
    }
}

extern "C" void kernel_launch(void* const* d_in, const int* in_sizes, int n_in,
                              void* d_out, int out_size, void* d_ws, size_t ws_size,
                              hipStream_t stream) {
    (void)in_sizes; (void)n_in; (void)out_size; (void)ws_size;
    const float* f0 = (const float*)d_in[0];
    const float* f1 = (const float*)d_in[1];
    float* out = (float*)d_out;
    float* scratch = (float*)d_ws;   // needs 162 * 24576 * 4 B = 15.93 MB

    corr_kernel<<<3456, 64, 0, stream>>>(f0, f1, scratch);
    softmax_kernel<<<384, 256, 0, stream>>>(scratch, out);
}